// Round 1
// baseline (307.743 us; speedup 1.0000x reference)
//
#include <hip/hip_runtime.h>
#include <math.h>

// ---------------- types ----------------
typedef __attribute__((ext_vector_type(8))) short short8;
typedef __attribute__((ext_vector_type(4))) float f32x4;

#define NB 2
#define LQ 2048
#define LK 2048
#define DM 1024
#define NH 16
#define HD 64

__device__ __forceinline__ unsigned short f2bf(float f) {
    unsigned u = __builtin_bit_cast(unsigned, f);
    u = (u + 0x7FFFu + ((u >> 16) & 1u)) >> 16;
    return (unsigned short)u;
}

__device__ __forceinline__ void gload16(const void* g, void* l) {
    __builtin_amdgcn_global_load_lds(
        (const __attribute__((address_space(1))) void*)g,
        (__attribute__((address_space(3))) void*)l, 16, 0, 0);
}

// ---------------- convert f32 -> bf16 ----------------
// layout (elements): Qb[0..4194304) Kb[..8388608) Wqb[..9437184) Wkb[..10485760) Wvb[..11534336)
__global__ __launch_bounds__(256) void convertk(
    const float* __restrict__ q, const float* __restrict__ k,
    const float* __restrict__ wq, const float* __restrict__ wk,
    const float* __restrict__ wv, unsigned short* __restrict__ dst)
{
    long i4 = (long)blockIdx.x * 256 + threadIdx.x;
    long e = i4 * 4;
    if (e >= 11534336L) return;
    const float* src; long off;
    if (e < 4194304L)       { src = q;  off = e; }
    else if (e < 8388608L)  { src = k;  off = e - 4194304L; }
    else if (e < 9437184L)  { src = wq; off = e - 8388608L; }
    else if (e < 10485760L) { src = wk; off = e - 9437184L; }
    else                    { src = wv; off = e - 10485760L; }
    float4 v = *(const float4*)(src + off);
    ushort4 r;
    r.x = f2bf(v.x); r.y = f2bf(v.y); r.z = f2bf(v.z); r.w = f2bf(v.w);
    *(ushort4*)(dst + e) = r;
}

// ---------------- valid-length / scaling ----------------
__global__ __launch_bounds__(256) void scalek(const unsigned char* __restrict__ pm,
                                              float* __restrict__ scal, int* __restrict__ vlen)
{
    __shared__ int red[256];
    int t = threadIdx.x;
    for (int n = 0; n < NB; n++) {
        int cnt = 0;
        for (int i = t; i < LK; i += 256) cnt += (pm[n * LK + i] == 0) ? 1 : 0;
        red[t] = cnt;
        __syncthreads();
        for (int s = 128; s > 0; s >>= 1) {
            if (t < s) red[t] += red[t + s];
            __syncthreads();
        }
        if (t == 0) { vlen[n] = red[0]; scal[n] = 1.0f / sqrtf((float)red[0]); }
        __syncthreads();
    }
}

// ---------------- projection GEMM: C = A * B^T  (all bf16, row-major, K=1024) ----------------
__global__ __launch_bounds__(256) void gemm3(
    const unsigned short* __restrict__ Qb, const unsigned short* __restrict__ Kb,
    const unsigned short* __restrict__ Wqb, const unsigned short* __restrict__ Wkb,
    const unsigned short* __restrict__ Wvb,
    unsigned short* __restrict__ Qp, unsigned short* __restrict__ Kp, unsigned short* __restrict__ Vp)
{
    const unsigned short *A, *B;
    unsigned short* C;
    int z = blockIdx.z;
    if (z == 0)      { A = Qb; B = Wqb; C = Qp; }
    else if (z == 1) { A = Kb; B = Wkb; C = Kp; }
    else             { A = Kb; B = Wvb; C = Vp; }
    const int K = DM, NN = DM;
    __shared__ unsigned short As[4096];  // [128][32]
    __shared__ unsigned short Bs[4096];  // [128][32]
    int t = threadIdx.x, wave = t >> 6, lane = t & 63;
    int bm = blockIdx.x * 128, bn = blockIdx.y * 128;
    int wr = (wave >> 1) * 64, wc = (wave & 1) * 64;
    // staging: issue0 element = wave*512 + lane*8 -> row wave*16 + lane/4, col (lane&3)*8
    int sr = wave * 16 + (lane >> 2);
    int sc = (lane & 3) * 8;
    int frow = lane & 15, fk = (lane >> 4) * 8;
    f32x4 zero = {0.f, 0.f, 0.f, 0.f};
    f32x4 acc[4][4];
    for (int i = 0; i < 4; i++) for (int j = 0; j < 4; j++) acc[i][j] = zero;

    for (int k0 = 0; k0 < K; k0 += 32) {
        const unsigned short* a0 = A + (size_t)(bm + sr) * K + k0 + sc;
        const unsigned short* b0 = B + (size_t)(bn + sr) * K + k0 + sc;
        gload16(a0, &As[wave * 512]);
        gload16(a0 + (size_t)64 * K, &As[2048 + wave * 512]);
        gload16(b0, &Bs[wave * 512]);
        gload16(b0 + (size_t)64 * K, &Bs[2048 + wave * 512]);
        __syncthreads();
        short8 af[4], bfr[4];
#pragma unroll
        for (int i = 0; i < 4; i++) af[i]  = *(const short8*)&As[(wr + i * 16 + frow) * 32 + fk];
#pragma unroll
        for (int j = 0; j < 4; j++) bfr[j] = *(const short8*)&Bs[(wc + j * 16 + frow) * 32 + fk];
#pragma unroll
        for (int i = 0; i < 4; i++)
#pragma unroll
            for (int j = 0; j < 4; j++)
                acc[i][j] = __builtin_amdgcn_mfma_f32_16x16x32_bf16(af[i], bfr[j], acc[i][j], 0, 0, 0);
        __syncthreads();
    }
    int ccol = lane & 15, crow = (lane >> 4) * 4;
#pragma unroll
    for (int i = 0; i < 4; i++)
#pragma unroll
        for (int j = 0; j < 4; j++) {
            int col = bn + wc + j * 16 + ccol;
#pragma unroll
            for (int r = 0; r < 4; r++) {
                int row = bm + wr + i * 16 + crow + r;
                C[(size_t)row * NN + col] = f2bf(acc[i][j][r]);
            }
        }
}

// ---------------- transpose V (per sentence 2048x1024 -> 1024x2048) ----------------
__global__ __launch_bounds__(256) void transposek(const unsigned short* __restrict__ V,
                                                  unsigned short* __restrict__ Vt)
{
    __shared__ unsigned short tile[64][65];
    int n = blockIdx.z;
    int k0 = blockIdx.x * 64, d0 = blockIdx.y * 64;
    int t = threadIdx.x;
#pragma unroll
    for (int it = 0; it < 2; it++) {
        int r = (t >> 3) + it * 32, c = (t & 7) * 8;
        short8 v = *(const short8*)&V[((size_t)(n * LK + k0 + r)) * DM + d0 + c];
#pragma unroll
        for (int j = 0; j < 8; j++) tile[r][c + j] = (unsigned short)v[j];
    }
    __syncthreads();
#pragma unroll
    for (int it = 0; it < 2; it++) {
        int r2 = (t >> 3) + it * 32, c2 = (t & 7) * 8;
        short8 v;
#pragma unroll
        for (int j = 0; j < 8; j++) v[j] = (short)tile[c2 + j][r2];
        *(short8*)&Vt[((size_t)(n * DM + d0 + r2)) * LK + k0 + c2] = v;
    }
}

// ---------------- flash attention ----------------
// block: 256 threads = 4 waves; each wave owns 16 q rows; q-tile = 64, k-tile = 64
__global__ __launch_bounds__(256) void attnk(
    const unsigned short* __restrict__ Qp, const unsigned short* __restrict__ Kp,
    const unsigned short* __restrict__ Vt,
    const float* __restrict__ scal, const int* __restrict__ vlenp,
    float* __restrict__ out)
{
    __shared__ unsigned short Qs[4096];  // [64 q][64 d]
    __shared__ unsigned short Ks[4096];  // [64 k][64 d]
    __shared__ unsigned short Vs[4096];  // [64 d][64 k]  (from Vt)
    __shared__ unsigned short Ps[4096];  // per wave [16 q][64 k]
    int t = threadIdx.x, wave = t >> 6, lane = t & 63;
    int nh = blockIdx.y, n = nh >> 4, h = nh & 15;
    int q0 = blockIdx.x * 64;
    float inv_scale = scal[n];
    int vlen = vlenp[n];
    int frow = lane & 15, fk = (lane >> 4) * 8;
    // staging: issue i: element = i*2048 + wave*512 + lane*8 -> row i*32 + wave*8 + (lane>>3), col (lane&7)*8
    int sr = wave * 8 + (lane >> 3), sc = (lane & 7) * 8;

    {   // Q tile once
        const unsigned short* g0 = Qp + (size_t)(n * LQ + q0 + sr) * DM + h * HD + sc;
        gload16(g0, &Qs[wave * 512]);
        gload16(g0 + (size_t)32 * DM, &Qs[2048 + wave * 512]);
    }

    f32x4 zero = {0.f, 0.f, 0.f, 0.f};
    f32x4 o[4];
    for (int dt = 0; dt < 4; dt++) o[dt] = zero;
    float m_run[4], l_run[4];
    for (int r = 0; r < 4; r++) { m_run[r] = -INFINITY; l_run[r] = 0.f; }

    int kend = min(q0 + 64, ((vlen + 63) >> 6) << 6);
    for (int k0 = 0; k0 < kend; k0 += 64) {
        const unsigned short* gk = Kp + (size_t)(n * LK + k0 + sr) * DM + h * HD + sc;
        gload16(gk, &Ks[wave * 512]);
        gload16(gk + (size_t)32 * DM, &Ks[2048 + wave * 512]);
        const unsigned short* gv = Vt + (size_t)(n * DM + h * HD + sr) * LK + k0 + sc;
        gload16(gv, &Vs[wave * 512]);
        gload16(gv + (size_t)32 * LK, &Vs[2048 + wave * 512]);
        __syncthreads();

        // S = Q K^T  (wave's 16 q rows x 64 keys)
        short8 aq0 = *(const short8*)&Qs[(wave * 16 + frow) * 64 + fk];
        short8 aq1 = *(const short8*)&Qs[(wave * 16 + frow) * 64 + 32 + fk];
        f32x4 s[4];
#pragma unroll
        for (int kt = 0; kt < 4; kt++) {
            short8 b0 = *(const short8*)&Ks[(kt * 16 + frow) * 64 + fk];
            short8 b1 = *(const short8*)&Ks[(kt * 16 + frow) * 64 + 32 + fk];
            f32x4 z = zero;
            z = __builtin_amdgcn_mfma_f32_16x16x32_bf16(aq0, b0, z, 0, 0, 0);
            z = __builtin_amdgcn_mfma_f32_16x16x32_bf16(aq1, b1, z, 0, 0, 0);
            s[kt] = z;
        }
        // scale + mask   (lane holds q = q0+wave*16+(lane>>4)*4+r , k = k0+kt*16+(lane&15))
        int kb = k0 + (lane & 15);
        int qg0 = q0 + wave * 16 + ((lane >> 4) << 2);
#pragma unroll
        for (int kt = 0; kt < 4; kt++)
#pragma unroll
            for (int r = 0; r < 4; r++) {
                float v = s[kt][r] * inv_scale;
                int kg = kb + kt * 16, qg = qg0 + r;
                if (kg > qg || kg >= vlen) v = -INFINITY;
                s[kt][r] = v;
            }
        // online softmax per q row
#pragma unroll
        for (int r = 0; r < 4; r++) {
            float mx = fmaxf(fmaxf(s[0][r], s[1][r]), fmaxf(s[2][r], s[3][r]));
            for (int off = 1; off < 16; off <<= 1) mx = fmaxf(mx, __shfl_xor(mx, off));
            float mn = fmaxf(m_run[r], mx);
            float al = __expf(m_run[r] - mn);
            float ssum = 0.f;
#pragma unroll
            for (int kt = 0; kt < 4; kt++) {
                float p = __expf(s[kt][r] - mn);
                s[kt][r] = p;
                ssum += p;
            }
            for (int off = 1; off < 16; off <<= 1) ssum += __shfl_xor(ssum, off);
            l_run[r] = l_run[r] * al + ssum;
            m_run[r] = mn;
#pragma unroll
            for (int dt = 0; dt < 4; dt++) o[dt][r] *= al;
        }
        // write P (bf16) to per-wave LDS: [16 q][64 k]
#pragma unroll
        for (int kt = 0; kt < 4; kt++)
#pragma unroll
            for (int r = 0; r < 4; r++)
                Ps[wave * 1024 + (((lane >> 4) << 2) + r) * 64 + kt * 16 + (lane & 15)] = f2bf(s[kt][r]);
        __syncthreads();
        // O += P V
#pragma unroll
        for (int ks = 0; ks < 2; ks++) {
            short8 ap = *(const short8*)&Ps[wave * 1024 + frow * 64 + ks * 32 + fk];
#pragma unroll
            for (int dt = 0; dt < 4; dt++) {
                short8 bv = *(const short8*)&Vs[(dt * 16 + frow) * 64 + ks * 32 + fk];
                o[dt] = __builtin_amdgcn_mfma_f32_16x16x32_bf16(ap, bv, o[dt], 0, 0, 0);
            }
        }
        __syncthreads();
    }
    // epilogue: out[n][q][h*64+d] = o / l
#pragma unroll
    for (int dt = 0; dt < 4; dt++)
#pragma unroll
        for (int r = 0; r < 4; r++) {
            int qg = q0 + wave * 16 + ((lane >> 4) << 2) + r;
            int dg = h * HD + dt * 16 + (lane & 15);
            out[((size_t)n * LQ + qg) * DM + dg] = o[dt][r] / l_run[r];
        }
}

// ---------------- launch ----------------
extern "C" void kernel_launch(void* const* d_in, const int* in_sizes, int n_in,
                              void* d_out, int out_size, void* d_ws, size_t ws_size,
                              hipStream_t stream) {
    const float* query = (const float*)d_in[0];
    const float* key   = (const float*)d_in[1];
    const float* Wq    = (const float*)d_in[2];
    const float* Wk    = (const float*)d_in[3];
    const float* Wv    = (const float*)d_in[4];
    const unsigned char* pmask = (const unsigned char*)d_in[6];
    float* out = (float*)d_out;

    char* ws = (char*)d_ws;
    unsigned short* bfbase = (unsigned short*)ws;          // converted inputs (elem offsets below)
    unsigned short* Qb  = bfbase;                          // 4096x1024
    unsigned short* Kb  = bfbase + 4194304L;               // 4096x1024
    unsigned short* Wqb = bfbase + 8388608L;               // 1024x1024
    unsigned short* Wkb = bfbase + 9437184L;
    unsigned short* Wvb = bfbase + 10485760L;
    unsigned short* Qp  = (unsigned short*)(ws + 23068672L);   // 4096x1024 bf16
    unsigned short* Kp  = (unsigned short*)(ws + 31457280L);
    unsigned short* Vp  = (unsigned short*)(ws + 39845888L);
    unsigned short* Vt  = (unsigned short*)(ws + 48234496L);   // [2][1024][2048]
    float* scal = (float*)(ws + 56623104L);
    int*   vlen = (int*)(ws + 56623104L + 64);

    convertk<<<11264, 256, 0, stream>>>(query, key, Wq, Wk, Wv, bfbase);
    scalek<<<1, 256, 0, stream>>>(pmask, scal, vlen);
    gemm3<<<dim3(32, 8, 3), 256, 0, stream>>>(Qb, Kb, Wqb, Wkb, Wvb, Qp, Kp, Vp);
    transposek<<<dim3(32, 16, 2), 256, 0, stream>>>(Vp, Vt);
    attnk<<<dim3(32, 32), 256, 0, stream>>>(Qp, Kp, Vt, scal, vlen, out);
}

// Round 2
// 288.447 us; speedup vs baseline: 1.0669x; 1.0669x over previous
//
#include <hip/hip_runtime.h>
#include <math.h>

// ---------------- types ----------------
typedef __attribute__((ext_vector_type(8))) short short8;
typedef __attribute__((ext_vector_type(4))) float f32x4;

#define NB 2
#define LQ 2048
#define LK 2048
#define DM 1024
#define NH 16
#define HD 64

__device__ __forceinline__ unsigned short f2bf(float f) {
    unsigned u = __builtin_bit_cast(unsigned, f);
    u = (u + 0x7FFFu + ((u >> 16) & 1u)) >> 16;
    return (unsigned short)u;
}

__device__ __forceinline__ void gload16(const void* g, void* l) {
    __builtin_amdgcn_global_load_lds(
        (const __attribute__((address_space(1))) void*)g,
        (__attribute__((address_space(3))) void*)l, 16, 0, 0);
}

// XOR-swizzled LDS accessors for [R][64] u16 tiles (row stride 128 B).
// byte ^= (row&7)<<4 spreads the 16B slots of 8 consecutive rows across banks.
__device__ __forceinline__ short8 lds_load8(const unsigned short* base, int row, int col) {
    int byte = (row * 128 + col * 2) ^ ((row & 7) << 4);
    return *(const short8*)((const char*)base + byte);
}
__device__ __forceinline__ void lds_store16(unsigned short* base, int row, int col, unsigned short v) {
    int byte = (row * 128 + col * 2) ^ ((row & 7) << 4);
    *(unsigned short*)((char*)base + byte) = v;
}

// ---------------- convert f32 -> bf16 ----------------
__global__ __launch_bounds__(256) void convertk(
    const float* __restrict__ q, const float* __restrict__ k,
    const float* __restrict__ wq, const float* __restrict__ wk,
    const float* __restrict__ wv, unsigned short* __restrict__ dst)
{
    long i4 = (long)blockIdx.x * 256 + threadIdx.x;
    long e = i4 * 4;
    if (e >= 11534336L) return;
    const float* src; long off;
    if (e < 4194304L)       { src = q;  off = e; }
    else if (e < 8388608L)  { src = k;  off = e - 4194304L; }
    else if (e < 9437184L)  { src = wq; off = e - 8388608L; }
    else if (e < 10485760L) { src = wk; off = e - 9437184L; }
    else                    { src = wv; off = e - 10485760L; }
    float4 v = *(const float4*)(src + off);
    ushort4 r;
    r.x = f2bf(v.x); r.y = f2bf(v.y); r.z = f2bf(v.z); r.w = f2bf(v.w);
    *(ushort4*)(dst + e) = r;
}

// ---------------- valid-length / scaling ----------------
__global__ __launch_bounds__(256) void scalek(const unsigned char* __restrict__ pm,
                                              float* __restrict__ scal, int* __restrict__ vlen)
{
    __shared__ int red[256];
    int t = threadIdx.x;
    for (int n = 0; n < NB; n++) {
        int cnt = 0;
        for (int i = t; i < LK; i += 256) cnt += (pm[n * LK + i] == 0) ? 1 : 0;
        red[t] = cnt;
        __syncthreads();
        for (int s = 128; s > 0; s >>= 1) {
            if (t < s) red[t] += red[t + s];
            __syncthreads();
        }
        if (t == 0) { vlen[n] = red[0]; scal[n] = 1.0f / sqrtf((float)red[0]); }
        __syncthreads();
    }
}

// ---------------- projection GEMM: C = A * B^T  (all bf16, row-major, K=1024) ----------------
__global__ __launch_bounds__(256) void gemm3(
    const unsigned short* __restrict__ Qb, const unsigned short* __restrict__ Kb,
    const unsigned short* __restrict__ Wqb, const unsigned short* __restrict__ Wkb,
    const unsigned short* __restrict__ Wvb,
    unsigned short* __restrict__ Qp, unsigned short* __restrict__ Kp, unsigned short* __restrict__ Vp)
{
    const unsigned short *A, *B;
    unsigned short* C;
    int z = blockIdx.z;
    if (z == 0)      { A = Qb; B = Wqb; C = Qp; }
    else if (z == 1) { A = Kb; B = Wkb; C = Kp; }
    else             { A = Kb; B = Wvb; C = Vp; }
    const int K = DM, NN = DM;
    __shared__ unsigned short As[4096];  // [128][32]
    __shared__ unsigned short Bs[4096];  // [128][32]
    int t = threadIdx.x, wave = t >> 6, lane = t & 63;
    int bm = blockIdx.x * 128, bn = blockIdx.y * 128;
    int wr = (wave >> 1) * 64, wc = (wave & 1) * 64;
    int sr = wave * 16 + (lane >> 2);
    int sc = (lane & 3) * 8;
    int frow = lane & 15, fk = (lane >> 4) * 8;
    f32x4 zero = {0.f, 0.f, 0.f, 0.f};
    f32x4 acc[4][4];
    for (int i = 0; i < 4; i++) for (int j = 0; j < 4; j++) acc[i][j] = zero;

    for (int k0 = 0; k0 < K; k0 += 32) {
        const unsigned short* a0 = A + (size_t)(bm + sr) * K + k0 + sc;
        const unsigned short* b0 = B + (size_t)(bn + sr) * K + k0 + sc;
        gload16(a0, &As[wave * 512]);
        gload16(a0 + (size_t)64 * K, &As[2048 + wave * 512]);
        gload16(b0, &Bs[wave * 512]);
        gload16(b0 + (size_t)64 * K, &Bs[2048 + wave * 512]);
        __syncthreads();
        short8 af[4], bfr[4];
#pragma unroll
        for (int i = 0; i < 4; i++) af[i]  = *(const short8*)&As[(wr + i * 16 + frow) * 32 + fk];
#pragma unroll
        for (int j = 0; j < 4; j++) bfr[j] = *(const short8*)&Bs[(wc + j * 16 + frow) * 32 + fk];
#pragma unroll
        for (int i = 0; i < 4; i++)
#pragma unroll
            for (int j = 0; j < 4; j++)
                acc[i][j] = __builtin_amdgcn_mfma_f32_16x16x32_bf16(af[i], bfr[j], acc[i][j], 0, 0, 0);
        __syncthreads();
    }
    int ccol = lane & 15, crow = (lane >> 4) * 4;
#pragma unroll
    for (int i = 0; i < 4; i++)
#pragma unroll
        for (int j = 0; j < 4; j++) {
            int col = bn + wc + j * 16 + ccol;
#pragma unroll
            for (int r = 0; r < 4; r++) {
                int row = bm + wr + i * 16 + crow + r;
                C[(size_t)row * NN + col] = f2bf(acc[i][j][r]);
            }
        }
}

// ---------------- transpose V (per sentence 2048x1024 -> 1024x2048) ----------------
__global__ __launch_bounds__(256) void transposek(const unsigned short* __restrict__ V,
                                                  unsigned short* __restrict__ Vt)
{
    __shared__ unsigned short tile[64][65];
    int n = blockIdx.z;
    int k0 = blockIdx.x * 64, d0 = blockIdx.y * 64;
    int t = threadIdx.x;
#pragma unroll
    for (int it = 0; it < 2; it++) {
        int r = (t >> 3) + it * 32, c = (t & 7) * 8;
        short8 v = *(const short8*)&V[((size_t)(n * LK + k0 + r)) * DM + d0 + c];
#pragma unroll
        for (int j = 0; j < 8; j++) tile[r][c + j] = (unsigned short)v[j];
    }
    __syncthreads();
#pragma unroll
    for (int it = 0; it < 2; it++) {
        int r2 = (t >> 3) + it * 32, c2 = (t & 7) * 8;
        short8 v;
#pragma unroll
        for (int j = 0; j < 8; j++) v[j] = (short)tile[c2 + j][r2];
        *(short8*)&Vt[((size_t)(n * DM + d0 + r2)) * LK + k0 + c2] = v;
    }
}

// ---------------- flash attention ----------------
// block: 256 threads = 4 waves; each wave owns 16 q rows; q-tile = 64, k-tile = 64
// LDS: swizzled tiles; K/V double-buffered; one barrier per k-tile.
__global__ __launch_bounds__(256) void attnk(
    const unsigned short* __restrict__ Qp, const unsigned short* __restrict__ Kp,
    const unsigned short* __restrict__ Vt,
    const float* __restrict__ scal, const int* __restrict__ vlenp,
    float* __restrict__ out)
{
    __shared__ unsigned short Qs[4096];        // [64 q][64 d]
    __shared__ unsigned short Ks[2][4096];     // [64 k][64 d] double buffered
    __shared__ unsigned short Vs[2][4096];     // [64 d][64 k] double buffered
    __shared__ unsigned short Ps[4096];        // per wave [16 q][64 k]
    int t = threadIdx.x, wave = t >> 6, lane = t & 63;
    int nh = blockIdx.y, n = nh >> 4, h = nh & 15;
    // reversed order: longest blocks (largest q0) dispatch first -> LPT scheduling
    int q0 = (int)(gridDim.x - 1 - blockIdx.x) * 64;
    float inv_scale = scal[n];
    int vlen = vlenp[n];
    int frow = lane & 15, fk = (lane >> 4) * 8;
    // staging geometry: linear LDS dest row = wave*8 + (lane>>3) (+32 for 2nd issue)
    int srl = lane >> 3;                 // row&7 of dest
    int sr = wave * 8 + srl;
    int scs = ((lane & 7) ^ srl) << 3;   // pre-swizzled source column (elements)

    {   // Q tile once (swizzled layout)
        const unsigned short* g0 = Qp + (size_t)(n * LQ + q0 + sr) * DM + h * HD + scs;
        gload16(g0, &Qs[wave * 512]);
        gload16(g0 + (size_t)32 * DM, &Qs[2048 + wave * 512]);
    }

    int nt = min(q0 / 64 + 1, (vlen + 63) >> 6);   // number of k-tiles
    // prologue: stage tile 0 into buffer 0
    {
        const unsigned short* gk = Kp + (size_t)(n * LK + sr) * DM + h * HD + scs;
        gload16(gk, &Ks[0][wave * 512]);
        gload16(gk + (size_t)32 * DM, &Ks[0][2048 + wave * 512]);
        const unsigned short* gv = Vt + (size_t)(n * DM + h * HD + sr) * LK + scs;
        gload16(gv, &Vs[0][wave * 512]);
        gload16(gv + (size_t)32 * LK, &Vs[0][2048 + wave * 512]);
    }
    __syncthreads();

    f32x4 zero = {0.f, 0.f, 0.f, 0.f};
    f32x4 o[4];
    for (int dt = 0; dt < 4; dt++) o[dt] = zero;
    float m_run[4], l_run[4];
    for (int r = 0; r < 4; r++) { m_run[r] = -INFINITY; l_run[r] = 0.f; }

    unsigned short* Pw = &Ps[wave * 1024];

    for (int ti = 0; ti < nt; ti++) {
        int cur = ti & 1;
        int k0 = ti * 64;
        if (ti + 1 < nt) {   // prefetch next tile into other buffer
            int k1 = k0 + 64;
            const unsigned short* gk = Kp + (size_t)(n * LK + k1 + sr) * DM + h * HD + scs;
            gload16(gk, &Ks[cur ^ 1][wave * 512]);
            gload16(gk + (size_t)32 * DM, &Ks[cur ^ 1][2048 + wave * 512]);
            const unsigned short* gv = Vt + (size_t)(n * DM + h * HD + sr) * LK + k1 + scs;
            gload16(gv, &Vs[cur ^ 1][wave * 512]);
            gload16(gv + (size_t)32 * LK, &Vs[cur ^ 1][2048 + wave * 512]);
        }

        // S = Q K^T  (wave's 16 q rows x 64 keys)
        short8 aq0 = lds_load8(Qs, wave * 16 + frow, 0 + fk);
        short8 aq1 = lds_load8(Qs, wave * 16 + frow, 32 + fk);
        f32x4 s[4];
#pragma unroll
        for (int kt = 0; kt < 4; kt++) {
            short8 b0 = lds_load8(Ks[cur], kt * 16 + frow, 0 + fk);
            short8 b1 = lds_load8(Ks[cur], kt * 16 + frow, 32 + fk);
            f32x4 z = zero;
            z = __builtin_amdgcn_mfma_f32_16x16x32_bf16(aq0, b0, z, 0, 0, 0);
            z = __builtin_amdgcn_mfma_f32_16x16x32_bf16(aq1, b1, z, 0, 0, 0);
            s[kt] = z;
        }
        // scale + mask   (lane holds q = q0+wave*16+(lane>>4)*4+r , k = k0+kt*16+(lane&15))
        int kb = k0 + (lane & 15);
        int qg0 = q0 + wave * 16 + ((lane >> 4) << 2);
#pragma unroll
        for (int kt = 0; kt < 4; kt++)
#pragma unroll
            for (int r = 0; r < 4; r++) {
                float v = s[kt][r] * inv_scale;
                int kg = kb + kt * 16, qg = qg0 + r;
                if (kg > qg || kg >= vlen) v = -INFINITY;
                s[kt][r] = v;
            }
        // online softmax per q row (reduce across the 16 lanes holding the row)
#pragma unroll
        for (int r = 0; r < 4; r++) {
            float mx = fmaxf(fmaxf(s[0][r], s[1][r]), fmaxf(s[2][r], s[3][r]));
            for (int off = 1; off < 16; off <<= 1) mx = fmaxf(mx, __shfl_xor(mx, off));
            float mn = fmaxf(m_run[r], mx);
            float al = __expf(m_run[r] - mn);
            float ssum = 0.f;
#pragma unroll
            for (int kt = 0; kt < 4; kt++) {
                float p = __expf(s[kt][r] - mn);
                s[kt][r] = p;
                ssum += p;
            }
            for (int off = 1; off < 16; off <<= 1) ssum += __shfl_xor(ssum, off);
            l_run[r] = l_run[r] * al + ssum;
            m_run[r] = mn;
#pragma unroll
            for (int dt = 0; dt < 4; dt++) o[dt][r] *= al;
        }
        // write P (bf16) to per-wave LDS (swizzled); no barrier needed (wave-private)
#pragma unroll
        for (int kt = 0; kt < 4; kt++)
#pragma unroll
            for (int r = 0; r < 4; r++)
                lds_store16(Pw, ((lane >> 4) << 2) + r, kt * 16 + (lane & 15), f2bf(s[kt][r]));
        // O += P V
#pragma unroll
        for (int ks = 0; ks < 2; ks++) {
            short8 ap = lds_load8(Pw, frow, ks * 32 + fk);
#pragma unroll
            for (int dt = 0; dt < 4; dt++) {
                short8 bv = lds_load8(Vs[cur], dt * 16 + frow, ks * 32 + fk);
                o[dt] = __builtin_amdgcn_mfma_f32_16x16x32_bf16(ap, bv, o[dt], 0, 0, 0);
            }
        }
        __syncthreads();   // staging of next tile complete + all waves done with cur
    }
    // epilogue: out[n][q][h*64+d] = o / l
#pragma unroll
    for (int dt = 0; dt < 4; dt++)
#pragma unroll
        for (int r = 0; r < 4; r++) {
            int qg = q0 + wave * 16 + ((lane >> 4) << 2) + r;
            int dg = h * HD + dt * 16 + (lane & 15);
            out[((size_t)n * LQ + qg) * DM + dg] = o[dt][r] / l_run[r];
        }
}

// ---------------- launch ----------------
extern "C" void kernel_launch(void* const* d_in, const int* in_sizes, int n_in,
                              void* d_out, int out_size, void* d_ws, size_t ws_size,
                              hipStream_t stream) {
    const float* query = (const float*)d_in[0];
    const float* key   = (const float*)d_in[1];
    const float* Wq    = (const float*)d_in[2];
    const float* Wk    = (const float*)d_in[3];
    const float* Wv    = (const float*)d_in[4];
    const unsigned char* pmask = (const unsigned char*)d_in[6];
    float* out = (float*)d_out;

    char* ws = (char*)d_ws;
    unsigned short* bfbase = (unsigned short*)ws;
    unsigned short* Qb  = bfbase;                          // 4096x1024
    unsigned short* Kb  = bfbase + 4194304L;               // 4096x1024
    unsigned short* Wqb = bfbase + 8388608L;
    unsigned short* Wkb = bfbase + 9437184L;
    unsigned short* Wvb = bfbase + 10485760L;
    unsigned short* Qp  = (unsigned short*)(ws + 23068672L);
    unsigned short* Kp  = (unsigned short*)(ws + 31457280L);
    unsigned short* Vp  = (unsigned short*)(ws + 39845888L);
    unsigned short* Vt  = (unsigned short*)(ws + 48234496L);   // [2][1024][2048]
    float* scal = (float*)(ws + 56623104L);
    int*   vlen = (int*)(ws + 56623104L + 64);

    convertk<<<11264, 256, 0, stream>>>(query, key, Wq, Wk, Wv, bfbase);
    scalek<<<1, 256, 0, stream>>>(pmask, scal, vlen);
    gemm3<<<dim3(32, 8, 3), 256, 0, stream>>>(Qb, Kb, Wqb, Wkb, Wvb, Qp, Kp, Vp);
    transposek<<<dim3(32, 16, 2), 256, 0, stream>>>(Vp, Vt);
    attnk<<<dim3(32, 32), 256, 0, stream>>>(Qp, Kp, Vt, scal, vlen, out);
}

// Round 3
// 197.764 us; speedup vs baseline: 1.5561x; 1.4585x over previous
//
#include <hip/hip_runtime.h>
#include <math.h>

// ---------------- types ----------------
typedef __attribute__((ext_vector_type(8))) short short8;
typedef __attribute__((ext_vector_type(4))) float f32x4;

#define NB 2
#define LQ 2048
#define LK 2048
#define DM 1024
#define NH 16
#define HD 64

__device__ __forceinline__ unsigned short f2bf(float f) {
    unsigned u = __builtin_bit_cast(unsigned, f);
    u = (u + 0x7FFFu + ((u >> 16) & 1u)) >> 16;
    return (unsigned short)u;
}

__device__ __forceinline__ void gload16(const void* g, void* l) {
    __builtin_amdgcn_global_load_lds(
        (const __attribute__((address_space(1))) void*)g,
        (__attribute__((address_space(3))) void*)l, 16, 0, 0);
}

__device__ __forceinline__ unsigned cvtpk(float a, float b) {
    unsigned r;
    asm("v_cvt_pk_bf16_f32 %0, %1, %2" : "=v"(r) : "v"(a), "v"(b));
    return r;
}

// XOR-swizzled LDS accessors for [R][64] u16 tiles (row stride 128 B).
__device__ __forceinline__ short8 lds_load8(const unsigned short* base, int row, int col) {
    int byte = (row * 128 + col * 2) ^ ((row & 7) << 4);
    return *(const short8*)((const char*)base + byte);
}

// ---------------- convert f32 -> bf16 ----------------
__global__ __launch_bounds__(256) void convertk(
    const float* __restrict__ q, const float* __restrict__ k,
    const float* __restrict__ wq, const float* __restrict__ wk,
    const float* __restrict__ wv, unsigned short* __restrict__ dst)
{
    long i4 = (long)blockIdx.x * 256 + threadIdx.x;
    long e = i4 * 4;
    if (e >= 11534336L) return;
    const float* src; long off;
    if (e < 4194304L)       { src = q;  off = e; }
    else if (e < 8388608L)  { src = k;  off = e - 4194304L; }
    else if (e < 9437184L)  { src = wq; off = e - 8388608L; }
    else if (e < 10485760L) { src = wk; off = e - 9437184L; }
    else                    { src = wv; off = e - 10485760L; }
    float4 v = *(const float4*)(src + off);
    ushort4 r;
    r.x = f2bf(v.x); r.y = f2bf(v.y); r.z = f2bf(v.z); r.w = f2bf(v.w);
    *(ushort4*)(dst + e) = r;
}

// ---------------- valid-length / scaling ----------------
__global__ __launch_bounds__(256) void scalek(const unsigned char* __restrict__ pm,
                                              float* __restrict__ scal, int* __restrict__ vlen)
{
    __shared__ int red[256];
    int t = threadIdx.x;
    for (int n = 0; n < NB; n++) {
        int cnt = 0;
        for (int i = t; i < LK; i += 256) cnt += (pm[n * LK + i] == 0) ? 1 : 0;
        red[t] = cnt;
        __syncthreads();
        for (int s = 128; s > 0; s >>= 1) {
            if (t < s) red[t] += red[t + s];
            __syncthreads();
        }
        if (t == 0) { vlen[n] = red[0]; scal[n] = 1.0f / sqrtf((float)red[0]); }
        __syncthreads();
    }
}

// ---------------- projection GEMM: C = A * B^T  (all bf16, row-major, K=1024) ----------------
__global__ __launch_bounds__(256) void gemm3(
    const unsigned short* __restrict__ Qb, const unsigned short* __restrict__ Kb,
    const unsigned short* __restrict__ Wqb, const unsigned short* __restrict__ Wkb,
    const unsigned short* __restrict__ Wvb,
    unsigned short* __restrict__ Qp, unsigned short* __restrict__ Kp, unsigned short* __restrict__ Vp)
{
    const unsigned short *A, *B;
    unsigned short* C;
    int z = blockIdx.z;
    if (z == 0)      { A = Qb; B = Wqb; C = Qp; }
    else if (z == 1) { A = Kb; B = Wkb; C = Kp; }
    else             { A = Kb; B = Wvb; C = Vp; }
    const int K = DM, NN = DM;
    __shared__ unsigned short As[4096];  // [128][32]
    __shared__ unsigned short Bs[4096];  // [128][32]
    int t = threadIdx.x, wave = t >> 6, lane = t & 63;
    int bm = blockIdx.x * 128, bn = blockIdx.y * 128;
    int wr = (wave >> 1) * 64, wc = (wave & 1) * 64;
    int sr = wave * 16 + (lane >> 2);
    int sc = (lane & 3) * 8;
    int frow = lane & 15, fk = (lane >> 4) * 8;
    f32x4 zero = {0.f, 0.f, 0.f, 0.f};
    f32x4 acc[4][4];
    for (int i = 0; i < 4; i++) for (int j = 0; j < 4; j++) acc[i][j] = zero;

    for (int k0 = 0; k0 < K; k0 += 32) {
        const unsigned short* a0 = A + (size_t)(bm + sr) * K + k0 + sc;
        const unsigned short* b0 = B + (size_t)(bn + sr) * K + k0 + sc;
        gload16(a0, &As[wave * 512]);
        gload16(a0 + (size_t)64 * K, &As[2048 + wave * 512]);
        gload16(b0, &Bs[wave * 512]);
        gload16(b0 + (size_t)64 * K, &Bs[2048 + wave * 512]);
        __syncthreads();
        short8 af[4], bfr[4];
#pragma unroll
        for (int i = 0; i < 4; i++) af[i]  = *(const short8*)&As[(wr + i * 16 + frow) * 32 + fk];
#pragma unroll
        for (int j = 0; j < 4; j++) bfr[j] = *(const short8*)&Bs[(wc + j * 16 + frow) * 32 + fk];
#pragma unroll
        for (int i = 0; i < 4; i++)
#pragma unroll
            for (int j = 0; j < 4; j++)
                acc[i][j] = __builtin_amdgcn_mfma_f32_16x16x32_bf16(af[i], bfr[j], acc[i][j], 0, 0, 0);
        __syncthreads();
    }
    int ccol = lane & 15, crow = (lane >> 4) * 4;
#pragma unroll
    for (int i = 0; i < 4; i++)
#pragma unroll
        for (int j = 0; j < 4; j++) {
            int col = bn + wc + j * 16 + ccol;
#pragma unroll
            for (int r = 0; r < 4; r++) {
                int row = bm + wr + i * 16 + crow + r;
                C[(size_t)row * NN + col] = f2bf(acc[i][j][r]);
            }
        }
}

// ---------------- transpose V (per sentence 2048x1024 -> 1024x2048) ----------------
__global__ __launch_bounds__(256) void transposek(const unsigned short* __restrict__ V,
                                                  unsigned short* __restrict__ Vt)
{
    __shared__ unsigned short tile[64][65];
    int n = blockIdx.z;
    int k0 = blockIdx.x * 64, d0 = blockIdx.y * 64;
    int t = threadIdx.x;
#pragma unroll
    for (int it = 0; it < 2; it++) {
        int r = (t >> 3) + it * 32, c = (t & 7) * 8;
        short8 v = *(const short8*)&V[((size_t)(n * LK + k0 + r)) * DM + d0 + c];
#pragma unroll
        for (int j = 0; j < 8; j++) tile[r][c + j] = (unsigned short)v[j];
    }
    __syncthreads();
#pragma unroll
    for (int it = 0; it < 2; it++) {
        int r2 = (t >> 3) + it * 32, c2 = (t & 7) * 8;
        short8 v;
#pragma unroll
        for (int j = 0; j < 8; j++) v[j] = (short)tile[c2 + j][r2];
        *(short8*)&Vt[((size_t)(n * DM + d0 + r2)) * LK + k0 + c2] = v;
    }
}

// ---------------- flash attention (swapped-QK^T, paired q-tiles) ----------------
// Block = 2 waves (128 thr). Each block handles two 32-row q-tiles: a = xs, b = 63-xs
// sharing one k-tile loop (uniform total work ~33 tile-units). Wave w owns 16 q rows
// of each phase. Swapped mfma(K,Q): lane holds full S-row slice for ONE q (q = lane&15).

__device__ __forceinline__ void stage_kv(const unsigned short* Kp, const unsigned short* Vt,
    unsigned short* KsB, unsigned short* VsB, int n, int h, int k0, int w, int srl, int scs)
{
#pragma unroll
    for (int i = 0; i < 4; i++) {
        int row = 8 * w + 16 * i + srl;
        gload16(Kp + (size_t)(n * LK + k0 + row) * DM + h * HD + scs, KsB + w * 512 + i * 1024);
        gload16(Vt + (size_t)(n * DM + h * HD + row) * LK + k0 + scs, VsB + w * 512 + i * 1024);
    }
}

__device__ __forceinline__ void attn_phase(
    const short8 (&kf)[4][2], const unsigned short* VsCur, unsigned short* PsW,
    const short8& qf0, const short8& qf1,
    int qw, int k0, int vlen, float c2,
    f32x4 (&o)[4], float& m_run, float& l_run, int lane)
{
    const int c = lane & 15, g = lane >> 4;
    const int fk = g * 8;
    f32x4 zero = {0.f, 0.f, 0.f, 0.f};
    f32x4 sv[4];
#pragma unroll
    for (int kt = 0; kt < 4; kt++) {
        f32x4 z = zero;
        z = __builtin_amdgcn_mfma_f32_16x16x32_bf16(kf[kt][0], qf0, z, 0, 0, 0);
        z = __builtin_amdgcn_mfma_f32_16x16x32_bf16(kf[kt][1], qf1, z, 0, 0, 0);
        sv[kt] = z;   // sv[kt][r] = S[k = k0+16kt+4g+r][q = qw+c]
    }
    bool full = (k0 + 63 <= qw) && (k0 + 64 <= vlen);
    if (!full) {
        int q = qw + c;
#pragma unroll
        for (int kt = 0; kt < 4; kt++)
#pragma unroll
            for (int r = 0; r < 4; r++) {
                int kg = k0 + kt * 16 + g * 4 + r;
                if (kg > q || kg >= vlen) sv[kt][r] = -INFINITY;
            }
    }
    // in-lane max over 16 + 2-hop cross-lane (lanes c, c+16, c+32, c+48 share q)
    float mx = fmaxf(fmaxf(sv[0][0], sv[0][1]), fmaxf(sv[0][2], sv[0][3]));
#pragma unroll
    for (int kt = 1; kt < 4; kt++)
        mx = fmaxf(mx, fmaxf(fmaxf(sv[kt][0], sv[kt][1]), fmaxf(sv[kt][2], sv[kt][3])));
    mx = fmaxf(mx, __shfl_xor(mx, 16));
    mx = fmaxf(mx, __shfl_xor(mx, 32));
    float mn = fmaxf(m_run, mx);
    float al = __builtin_amdgcn_exp2f((m_run - mn) * c2);
    float ssum = 0.f;
#pragma unroll
    for (int kt = 0; kt < 4; kt++)
#pragma unroll
        for (int r = 0; r < 4; r++) {
            float p = __builtin_amdgcn_exp2f((sv[kt][r] - mn) * c2);
            sv[kt][r] = p;
            ssum += p;
        }
    ssum += __shfl_xor(ssum, 16);
    ssum += __shfl_xor(ssum, 32);
    l_run = l_run * al + ssum;
    m_run = mn;
    // broadcast al to o-row ownership (o rows are q-local 4g+r) and rescale
    float alr[4];
#pragma unroll
    for (int r = 0; r < 4; r++) alr[r] = __shfl(al, 4 * g + r);
#pragma unroll
    for (int dt = 0; dt < 4; dt++)
#pragma unroll
        for (int r = 0; r < 4; r++) o[dt][r] *= alr[r];
    // pack P (bf16 pairs) -> wave-private LDS [16 q][64 k], swizzled
#pragma unroll
    for (int kt = 0; kt < 4; kt++) {
        uint2 pw;
        pw.x = cvtpk(sv[kt][0], sv[kt][1]);
        pw.y = cvtpk(sv[kt][2], sv[kt][3]);
        int byte = (c * 128 + (kt * 16 + g * 4) * 2) ^ ((c & 7) << 4);
        *(uint2*)((char*)PsW + byte) = pw;
    }
    // O += P V  (A = P rows=q, B = V^T rows=d  ->  D[q-local][d])
#pragma unroll
    for (int ks = 0; ks < 2; ks++) {
        short8 ap = lds_load8(PsW, c, ks * 32 + fk);
#pragma unroll
        for (int dt = 0; dt < 4; dt++) {
            short8 bv = lds_load8(VsCur, dt * 16 + c, ks * 32 + fk);
            o[dt] = __builtin_amdgcn_mfma_f32_16x16x32_bf16(ap, bv, o[dt], 0, 0, 0);
        }
    }
}

__device__ __forceinline__ void attn_epilogue(float* out, const f32x4 (&o)[4], float l_run,
                                              int n, int h, int qw, int lane)
{
    int c = lane & 15, g = lane >> 4;
    float lr[4];
#pragma unroll
    for (int r = 0; r < 4; r++) lr[r] = __shfl(l_run, 4 * g + r);
#pragma unroll
    for (int dt = 0; dt < 4; dt++)
#pragma unroll
        for (int r = 0; r < 4; r++) {
            int q = qw + 4 * g + r;
            int d = h * HD + dt * 16 + c;
            out[((size_t)n * LQ + q) * DM + d] = o[dt][r] / lr[r];
        }
}

__global__ __launch_bounds__(128, 2) void attnk(
    const unsigned short* __restrict__ Qp, const unsigned short* __restrict__ Kp,
    const unsigned short* __restrict__ Vt,
    const float* __restrict__ scal, const int* __restrict__ vlenp,
    float* __restrict__ out)
{
    __shared__ unsigned short Ks[2][4096];     // [64 k][64 d] swizzled, dbuf
    __shared__ unsigned short Vs[2][4096];     // [64 d][64 k] swizzled, dbuf
    __shared__ unsigned short Ps[2][2][1024];  // [wave][phase][16 q][64 k]
    int t = threadIdx.x, w = t >> 6, lane = t & 63;
    // XCD swizzle: same (n,h) -> same XCD; x rotated per round for CU balance
    int bid = blockIdx.x;
    int r3 = bid >> 8;                        // 0..3
    int xs = ((bid >> 3) + (r3 << 3)) & 31;   // paired-tile index 0..31
    int y  = (bid & 7) * 4 + r3;              // (n,h) 0..31
    int n = y >> 4, h = y & 15;
    int qwA = xs * 32 + 16 * w;
    int qwB = (63 - xs) * 32 + 16 * w;
    float c2 = scal[n] * 1.4426950408889634f;
    int vlen = vlenp[n];
    int kvt = (vlen + 63) >> 6;
    int ntA = min((xs >> 1) + 1, kvt);
    int ntB = min(((63 - xs) >> 1) + 1, kvt);
    int frow = lane & 15, fk = (lane >> 4) * 8;
    int srl = lane >> 3;
    int scs = ((lane & 7) ^ srl) << 3;   // pre-swizzled source column

    // Q fragments direct to registers (B-operand layout: row = lane&15)
    const unsigned short* qA = Qp + (size_t)(n * LQ + qwA + frow) * DM + h * HD;
    const unsigned short* qB = Qp + (size_t)(n * LQ + qwB + frow) * DM + h * HD;
    short8 qA0 = *(const short8*)(qA + fk), qA1 = *(const short8*)(qA + 32 + fk);
    short8 qB0 = *(const short8*)(qB + fk), qB1 = *(const short8*)(qB + 32 + fk);

    stage_kv(Kp, Vt, Ks[0], Vs[0], n, h, 0, w, srl, scs);
    __syncthreads();

    f32x4 zero = {0.f, 0.f, 0.f, 0.f};
    f32x4 oA[4] = {zero, zero, zero, zero};
    f32x4 oB[4] = {zero, zero, zero, zero};
    float mA = -INFINITY, lA = 0.f, mB = -INFINITY, lB = 0.f;

    int ti = 0;
    for (; ti < ntA; ti++) {
        int cur = ti & 1, k0 = ti * 64;
        if (ti + 1 < ntB) stage_kv(Kp, Vt, Ks[cur ^ 1], Vs[cur ^ 1], n, h, k0 + 64, w, srl, scs);
        short8 kf[4][2];
#pragma unroll
        for (int kt = 0; kt < 4; kt++) {
            kf[kt][0] = lds_load8(Ks[cur], kt * 16 + frow, fk);
            kf[kt][1] = lds_load8(Ks[cur], kt * 16 + frow, 32 + fk);
        }
        attn_phase(kf, Vs[cur], &Ps[w][0][0], qA0, qA1, qwA, k0, vlen, c2, oA, mA, lA, lane);
        attn_phase(kf, Vs[cur], &Ps[w][1][0], qB0, qB1, qwB, k0, vlen, c2, oB, mB, lB, lane);
        __syncthreads();
    }
    attn_epilogue(out, oA, lA, n, h, qwA, lane);
    for (; ti < ntB; ti++) {
        int cur = ti & 1, k0 = ti * 64;
        if (ti + 1 < ntB) stage_kv(Kp, Vt, Ks[cur ^ 1], Vs[cur ^ 1], n, h, k0 + 64, w, srl, scs);
        short8 kf[4][2];
#pragma unroll
        for (int kt = 0; kt < 4; kt++) {
            kf[kt][0] = lds_load8(Ks[cur], kt * 16 + frow, fk);
            kf[kt][1] = lds_load8(Ks[cur], kt * 16 + frow, 32 + fk);
        }
        attn_phase(kf, Vs[cur], &Ps[w][1][0], qB0, qB1, qwB, k0, vlen, c2, oB, mB, lB, lane);
        __syncthreads();
    }
    attn_epilogue(out, oB, lB, n, h, qwB, lane);
}

// ---------------- launch ----------------
extern "C" void kernel_launch(void* const* d_in, const int* in_sizes, int n_in,
                              void* d_out, int out_size, void* d_ws, size_t ws_size,
                              hipStream_t stream) {
    const float* query = (const float*)d_in[0];
    const float* key   = (const float*)d_in[1];
    const float* Wq    = (const float*)d_in[2];
    const float* Wk    = (const float*)d_in[3];
    const float* Wv    = (const float*)d_in[4];
    const unsigned char* pmask = (const unsigned char*)d_in[6];
    float* out = (float*)d_out;

    char* ws = (char*)d_ws;
    unsigned short* bfbase = (unsigned short*)ws;
    unsigned short* Qb  = bfbase;                          // 4096x1024
    unsigned short* Kb  = bfbase + 4194304L;               // 4096x1024
    unsigned short* Wqb = bfbase + 8388608L;
    unsigned short* Wkb = bfbase + 9437184L;
    unsigned short* Wvb = bfbase + 10485760L;
    unsigned short* Qp  = (unsigned short*)(ws + 23068672L);
    unsigned short* Kp  = (unsigned short*)(ws + 31457280L);
    unsigned short* Vp  = (unsigned short*)(ws + 39845888L);
    unsigned short* Vt  = (unsigned short*)(ws + 48234496L);   // [2][1024][2048]
    float* scal = (float*)(ws + 56623104L);
    int*   vlen = (int*)(ws + 56623104L + 64);

    convertk<<<11264, 256, 0, stream>>>(query, key, Wq, Wk, Wv, bfbase);
    scalek<<<1, 256, 0, stream>>>(pmask, scal, vlen);
    gemm3<<<dim3(32, 8, 3), 256, 0, stream>>>(Qb, Kb, Wqb, Wkb, Wvb, Qp, Kp, Vp);
    transposek<<<dim3(32, 16, 2), 256, 0, stream>>>(Vp, Vt);
    attnk<<<1024, 128, 0, stream>>>(Qp, Kp, Vt, scal, vlen, out);
}